// Round 8
// baseline (232.177 us; speedup 1.0000x reference)
//
#include <hip/hip_runtime.h>
#include <hip/hip_bf16.h>
#include <math.h>

#define TB 2048   // sequence length
#define NB 4      // batch
#define NH 8      // heads
#define HD 96     // head dim
#define KD 768    // model dim

typedef unsigned short u16;
typedef __attribute__((ext_vector_type(4))) u16 u16x4;
typedef __attribute__((ext_vector_type(8))) u16 u16x8;
typedef __attribute__((ext_vector_type(4))) float f32x4;
typedef __attribute__((ext_vector_type(16))) float f32x16;
typedef __attribute__((ext_vector_type(4))) unsigned u32x4;
typedef __attribute__((ext_vector_type(8))) __bf16 bf16x8;

__device__ __forceinline__ u16 f2bf(float f) {
    unsigned u = __builtin_bit_cast(unsigned, f);
    u += 0x7FFFu + ((u >> 16) & 1u);   // RNE
    return (u16)(u >> 16);
}
__device__ __forceinline__ bf16x8 cast8(u16x8 u) { return __builtin_bit_cast(bf16x8, u); }
__device__ __forceinline__ unsigned pkbf(float a, float b) {
    unsigned w;
    asm("v_cvt_pk_bf16_f32 %0, %1, %2" : "=v"(w) : "v"(a), "v"(b));
    return w;
}

// ---------------------------------------------------------------------------
// Kernel A: QKV projection with LDS-repacked coalesced stores.
//   Q,K -> [bh][t][96] ; V -> [bh][96][t] (transposed via swapped MFMA).
// All global stores go through a repack tile -> b128 chunks (128-192B segs).
// grid = (32 t-chunks, 32 bh), 256 thr.
// ---------------------------------------------------------------------------
__global__ __launch_bounds__(256) void qkv_proj(
    const float* __restrict__ x, const float* __restrict__ Wq,
    const float* __restrict__ Wk, const float* __restrict__ Wv,
    u16* __restrict__ Q, u16* __restrict__ Kout, u16* __restrict__ VT, float inv4)
{
    __shared__ __align__(16) u16 Wl[3][96][104];
    __shared__ __align__(16) u16 Rp[96 * 72];   // union: Q/K [64][104], V [96][72]
    const int tid = threadIdx.x;
    for (int idx = tid; idx < 3 * 9216; idx += 256) {
        int m = idx / 9216, rem = idx % 9216;
        const float* Wsrc = (m == 0) ? Wq : (m == 1) ? Wk : Wv;
        float scale = (m < 2) ? inv4 : 1.0f;
        int r = rem / 96, c = rem % 96;
        Wl[m][r][c] = f2bf(Wsrc[rem] * scale);
    }
    __syncthreads();

    const int w = tid >> 6, l = tid & 63;
    const int lc = l & 15, lk = l >> 4;
    const int bh = blockIdx.y, b = bh >> 3, h = bh & 7;
    const int t0 = blockIdx.x * 64;
    const int tw = t0 + w * 16;

    bf16x8 afrag[3];
    {
        const float* xp = x + ((long)((b * TB + tw + lc) * NH + h)) * HD + 8 * lk;
#pragma unroll
        for (int c = 0; c < 3; ++c) {
            f32x4 f0 = *(const f32x4*)(xp + c * 32);
            f32x4 f1 = *(const f32x4*)(xp + c * 32 + 4);
            u16x8 u;
#pragma unroll
            for (int j = 0; j < 4; ++j) { u[j] = f2bf(f0[j]); u[4 + j] = f2bf(f1[j]); }
            afrag[c] = cast8(u);
        }
    }

    const f32x4 Z4 = {0.f, 0.f, 0.f, 0.f};
    u16* outs[2] = {Q, Kout};
#pragma unroll
    for (int m = 0; m < 2; ++m) {
        f32x4 acc[6];
#pragma unroll
        for (int nt = 0; nt < 6; ++nt) acc[nt] = Z4;
#pragma unroll
        for (int c = 0; c < 3; ++c) {
#pragma unroll
            for (int nt = 0; nt < 6; ++nt) {
                u16x8 bw = *(const u16x8*)&Wl[m][nt * 16 + lc][c * 32 + 8 * lk];
                acc[nt] = __builtin_amdgcn_mfma_f32_16x16x32_bf16(afrag[c], cast8(bw), acc[nt], 0, 0, 0);
            }
        }
        __syncthreads();   // Rp free (prior reads done)
#pragma unroll
        for (int nt = 0; nt < 6; ++nt)
#pragma unroll
            for (int reg = 0; reg < 4; ++reg)
                Rp[(w * 16 + lk * 4 + reg) * 104 + nt * 16 + lc] = f2bf(acc[nt][reg]);
        __syncthreads();
#pragma unroll
        for (int ci = 0; ci < 3; ++ci) {
            int ch = tid + ci * 256;
            int row = ch / 12, cc = (ch % 12) * 8;
            *(u16x8*)(outs[m] + ((long)bh * TB + t0 + row) * HD + cc) = *(const u16x8*)&Rp[row * 104 + cc];
        }
    }
    {   // V transposed: D[o][t] via swapped args
        f32x4 acc[6];
#pragma unroll
        for (int nt = 0; nt < 6; ++nt) acc[nt] = Z4;
#pragma unroll
        for (int c = 0; c < 3; ++c) {
#pragma unroll
            for (int nt = 0; nt < 6; ++nt) {
                u16x8 aw = *(const u16x8*)&Wl[2][nt * 16 + lc][c * 32 + 8 * lk];
                acc[nt] = __builtin_amdgcn_mfma_f32_16x16x32_bf16(cast8(aw), afrag[c], acc[nt], 0, 0, 0);
            }
        }
        __syncthreads();
#pragma unroll
        for (int nt = 0; nt < 6; ++nt)
#pragma unroll
            for (int reg = 0; reg < 4; ++reg) {
                int o = nt * 16 + lk * 4 + reg;
                Rp[o * 72 + w * 16 + lc] = f2bf(acc[nt][reg]);
            }
        __syncthreads();
#pragma unroll
        for (int ci = 0; ci < 3; ++ci) {
            int ch = tid + ci * 256;
            int row = ch >> 3, tc = (ch & 7) * 8;
            *(u16x8*)(VT + ((long)bh * HD + row) * TB + t0 + tc) = *(const u16x8*)&Rp[row * 72 + tc];
        }
    }
}

// ---------------------------------------------------------------------------
// Kernel B: flash attention, q=64/wave (2 Q-fragment sets -> 2 MFMA per LDS
// read), KVBLK=32, 4-wave blocks (q-tile 256), dbuf 1-barrier, XCD swizzle.
// grid = 256 blocks (8 qtiles x 32 bh), 256 thr.
// ---------------------------------------------------------------------------
#define KVB 32
#define VOFF2 (KVB * 104)              // 3328 elems
#define SLAB2 (KVB * 104 + 96 * 40)    // 7168 elems = 14336 B

__global__ __launch_bounds__(256) void attn(
    const u16* __restrict__ Q, const u16* __restrict__ Kin, const u16* __restrict__ VT,
    u16* __restrict__ O)
{
    __shared__ __align__(16) u16 SM[2][SLAB2];

    const int tid = threadIdx.x;
    const int w = tid >> 6, l = tid & 63;
    const int m32 = l & 31, hi = l >> 5;
    const int lid = (blockIdx.x & 7) * 32 + (blockIdx.x >> 3);  // XCD swizzle (256%8==0)
    const int qt = lid & 7, bh = lid >> 3;
    const int q0 = qt * 256 + w * 64;

    const u16* Qb = Q + (long)bh * TB * HD;
    const u16* Kb = Kin + (long)bh * TB * HD;
    const u16* Vb = VT + (long)bh * HD * TB;    // [d][t]

    // staging: 3 b128 chunks/thread (K: 384 chunks, Vt: 384)
    const u16* gbase[3]; int loff[3]; int mult[3];
#pragma unroll
    for (int ci = 0; ci < 3; ++ci) {
        int ch = tid + ci * 256;
        if (ch < 384) {
            int row = ch / 12, cc = (ch % 12) * 8;
            gbase[ci] = Kb + row * HD + cc;
            mult[ci] = HD;
            loff[ci] = row * 104 + cc;
        } else {
            int c2 = ch - 384;
            int d = c2 >> 2, sc = (c2 & 3) * 8;
            gbase[ci] = Vb + (long)d * TB + sc;
            mult[ci] = 1;
            loff[ci] = VOFF2 + d * 40 + sc;
        }
    }

    // Q B-fragments, 2 q-sets: col q = q0 + qs*32 + m32, k = kk*16 + 8*hi + j
    bf16x8 qb[2][6];
#pragma unroll
    for (int qs = 0; qs < 2; ++qs)
#pragma unroll
        for (int kk = 0; kk < 6; ++kk)
            qb[qs][kk] = cast8(*(const u16x8*)(Qb + (long)(q0 + qs * 32 + m32) * HD + kk * 16 + 8 * hi));

    // prologue: tile0 -> SM[0], prefetch tile1
    u16x8 r[3];
#pragma unroll
    for (int ci = 0; ci < 3; ++ci) r[ci] = *(const u16x8*)(gbase[ci]);
#pragma unroll
    for (int ci = 0; ci < 3; ++ci) *(u16x8*)(SM[0] + loff[ci]) = r[ci];
#pragma unroll
    for (int ci = 0; ci < 3; ++ci) r[ci] = *(const u16x8*)(gbase[ci] + (long)KVB * mult[ci]);

    float m_st[2] = {-1e30f, -1e30f}, l_st[2] = {0.f, 0.f};
    f32x16 accO[3][2];                  // [d-tile][q-set]
#pragma unroll
    for (int dt = 0; dt < 3; ++dt)
#pragma unroll
        for (int qs = 0; qs < 2; ++qs)
#pragma unroll
            for (int rr = 0; rr < 16; ++rr) accO[dt][qs][rr] = 0.f;

    const int NST = TB / KVB;   // 64
    for (int st = 0; st < NST; ++st) {
        __syncthreads();
        if (st < NST - 1) {
            u16* dst = SM[(st + 1) & 1];
#pragma unroll
            for (int ci = 0; ci < 3; ++ci) *(u16x8*)(dst + loff[ci]) = r[ci];
            int s2 = (st + 2 < NST ? st + 2 : NST - 1) * KVB;
#pragma unroll
            for (int ci = 0; ci < 3; ++ci) r[ci] = *(const u16x8*)(gbase[ci] + (long)s2 * mult[ci]);
        }
        const u16* KP = SM[st & 1];
        const u16* VP = SM[st & 1] + VOFF2;

        // S^T = K Q^T: A = K rows (s = m32), B = qb[qs] -> one K read, 2 MFMA
        f32x16 sa[2];
#pragma unroll
        for (int qs = 0; qs < 2; ++qs)
#pragma unroll
            for (int rr = 0; rr < 16; ++rr) sa[qs][rr] = 0.f;
        __builtin_amdgcn_s_setprio(1);
#pragma unroll
        for (int kk = 0; kk < 6; ++kk) {
            u16x8 kf = *(const u16x8*)(KP + m32 * 104 + kk * 16 + 8 * hi);
            sa[0] = __builtin_amdgcn_mfma_f32_32x32x16_bf16(cast8(kf), qb[0][kk], sa[0], 0, 0, 0);
            sa[1] = __builtin_amdgcn_mfma_f32_32x32x16_bf16(cast8(kf), qb[1][kk], sa[1], 0, 0, 0);
        }
        __builtin_amdgcn_s_setprio(0);

        // online softmax per q-set (lane holds 16 of 32 s; partner at lane^32)
        float tm[2];
#pragma unroll
        for (int qs = 0; qs < 2; ++qs) {
            float t2 = sa[qs][0];
#pragma unroll
            for (int rr = 1; rr < 16; ++rr) t2 = fmaxf(t2, sa[qs][rr]);
            t2 = fmaxf(t2, __shfl_xor(t2, 32));
            tm[qs] = t2;
        }
        if (!__all(tm[0] - m_st[0] <= 8.0f && tm[1] - m_st[1] <= 8.0f)) {   // T13
#pragma unroll
            for (int qs = 0; qs < 2; ++qs) {
                float mnew = fmaxf(m_st[qs], tm[qs]);
                float alpha = __expf(m_st[qs] - mnew);
#pragma unroll
                for (int dt = 0; dt < 3; ++dt)
#pragma unroll
                    for (int rr = 0; rr < 16; ++rr) accO[dt][qs][rr] *= alpha;
                l_st[qs] *= alpha;
                m_st[qs] = mnew;
            }
        }
#pragma unroll
        for (int qs = 0; qs < 2; ++qs) {
            float sum = 0.f;
#pragma unroll
            for (int rr = 0; rr < 16; ++rr) {
                float pv = __expf(sa[qs][rr] - m_st[qs]);
                sa[qs][rr] = pv;
                sum += pv;
            }
            sum += __shfl_xor(sum, 32);
            l_st[qs] += sum;
        }

        // P -> bf16 B-fragments in-register (per q-set): pb0 k=s0..15, pb1 k=s16..31
        bf16x8 pb0[2], pb1[2];
#pragma unroll
        for (int qs = 0; qs < 2; ++qs) {
            unsigned A1 = pkbf(sa[qs][0], sa[qs][1]);
            unsigned A2 = pkbf(sa[qs][2], sa[qs][3]);
            unsigned B1 = pkbf(sa[qs][4], sa[qs][5]);
            unsigned B2 = pkbf(sa[qs][6], sa[qs][7]);
            unsigned A3 = pkbf(sa[qs][8], sa[qs][9]);
            unsigned A4 = pkbf(sa[qs][10], sa[qs][11]);
            unsigned B3 = pkbf(sa[qs][12], sa[qs][13]);
            unsigned B4 = pkbf(sa[qs][14], sa[qs][15]);
            unsigned xA1 = __shfl_xor((int)A1, 32), xA2 = __shfl_xor((int)A2, 32);
            unsigned xB1 = __shfl_xor((int)B1, 32), xB2 = __shfl_xor((int)B2, 32);
            unsigned xA3 = __shfl_xor((int)A3, 32), xA4 = __shfl_xor((int)A4, 32);
            unsigned xB3 = __shfl_xor((int)B3, 32), xB4 = __shfl_xor((int)B4, 32);
            u32x4 t0v = { hi ? xB1 : A1, hi ? xB2 : A2, hi ? B1 : xA1, hi ? B2 : xA2 };
            u32x4 t1v = { hi ? xB3 : A3, hi ? xB4 : A4, hi ? B3 : xA3, hi ? B4 : xA4 };
            pb0[qs] = __builtin_bit_cast(bf16x8, t0v);
            pb1[qs] = __builtin_bit_cast(bf16x8, t1v);
        }

        // PV: one V read -> 2 MFMA (both q-sets)
        __builtin_amdgcn_s_setprio(1);
#pragma unroll
        for (int dt = 0; dt < 3; ++dt) {
            u16x8 vf0 = *(const u16x8*)(VP + (dt * 32 + m32) * 40 + 8 * hi);
            accO[dt][0] = __builtin_amdgcn_mfma_f32_32x32x16_bf16(cast8(vf0), pb0[0], accO[dt][0], 0, 0, 0);
            accO[dt][1] = __builtin_amdgcn_mfma_f32_32x32x16_bf16(cast8(vf0), pb0[1], accO[dt][1], 0, 0, 0);
            u16x8 vf1 = *(const u16x8*)(VP + (dt * 32 + m32) * 40 + 16 + 8 * hi);
            accO[dt][0] = __builtin_amdgcn_mfma_f32_32x32x16_bf16(cast8(vf1), pb1[0], accO[dt][0], 0, 0, 0);
            accO[dt][1] = __builtin_amdgcn_mfma_f32_32x32x16_bf16(cast8(vf1), pb1[1], accO[dt][1], 0, 0, 0);
        }
        __builtin_amdgcn_s_setprio(0);
    }

    // epilogue: accO[dt][qs] rows d = (reg&3)+8*(reg>>2)+4*hi, col t = q0+qs*32+m32
    const int b = bh >> 3, h = bh & 7;
#pragma unroll
    for (int qs = 0; qs < 2; ++qs) {
        float linv = 1.0f / l_st[qs];
        int t = q0 + qs * 32 + m32;
        u16* op = O + ((long)(b * TB + t)) * KD + h * HD;
#pragma unroll
        for (int dt = 0; dt < 3; ++dt)
#pragma unroll
            for (int g = 0; g < 4; ++g) {
                u16x4 v = { f2bf(accO[dt][qs][g * 4 + 0] * linv), f2bf(accO[dt][qs][g * 4 + 1] * linv),
                            f2bf(accO[dt][qs][g * 4 + 2] * linv), f2bf(accO[dt][qs][g * 4 + 3] * linv) };
                *(u16x4*)(op + dt * 32 + g * 8 + 4 * hi) = v;
            }
    }
}

// ---------------------------------------------------------------------------
// Kernel C0: one-time Wu fp32 -> bf16 (into dead Q workspace region)
// ---------------------------------------------------------------------------
__global__ __launch_bounds__(256) void wu_conv(const float* __restrict__ Wu, u16* __restrict__ Wub) {
    int i = (blockIdx.x * 256 + threadIdx.x) * 4;
    f32x4 f = *(const f32x4*)(Wu + i);
    u16x4 o = { f2bf(f[0]), f2bf(f[1]), f2bf(f[2]), f2bf(f[3]) };
    *(u16x4*)(Wub + i) = o;
}

// ---------------------------------------------------------------------------
// Kernel C: out = O @ Wub^T + bu.  128x128 tile, BK=64, 32x32 MFMA, dbuf
// single-barrier, reg-prefetch.  4 waves (2x2).  1D grid 384, XCD swizzle.
// ---------------------------------------------------------------------------
__global__ __launch_bounds__(256) void out_gemm(
    const u16* __restrict__ O, const u16* __restrict__ Wub,
    const float* __restrict__ bu, float* __restrict__ out)
{
    __shared__ __align__(16) u16 Al[2][128][68];
    __shared__ __align__(16) u16 Bl[2][128][68];
    const int tid = threadIdx.x;
    const int w = tid >> 6, l = tid & 63;
    const int m32 = l & 31, hi = l >> 5;
    const int wr = w >> 1, wc = w & 1;
    const int lid = (blockIdx.x & 7) * 48 + (blockIdx.x >> 3);
    const int nb = lid % 6, mb = lid / 6;
    const int m0 = mb * 128, n0 = nb * 128;

    const int crow = tid >> 3, ccol = (tid & 7) * 8;

    f32x16 acc[2][2];
#pragma unroll
    for (int i = 0; i < 2; ++i)
#pragma unroll
        for (int j = 0; j < 2; ++j)
#pragma unroll
            for (int rr = 0; rr < 16; ++rr) acc[i][j][rr] = 0.f;

    u16x8 ra[4], rb[4];
#pragma unroll
    for (int i = 0; i < 4; ++i) {
        ra[i] = *(const u16x8*)(O   + (long)(m0 + crow + i * 32) * KD + ccol);
        rb[i] = *(const u16x8*)(Wub + (long)(n0 + crow + i * 32) * KD + ccol);
    }
#pragma unroll
    for (int i = 0; i < 4; ++i) {
        *(u16x8*)&Al[0][crow + i * 32][ccol] = ra[i];
        *(u16x8*)&Bl[0][crow + i * 32][ccol] = rb[i];
    }
#pragma unroll
    for (int i = 0; i < 4; ++i) {
        ra[i] = *(const u16x8*)(O   + (long)(m0 + crow + i * 32) * KD + 64 + ccol);
        rb[i] = *(const u16x8*)(Wub + (long)(n0 + crow + i * 32) * KD + 64 + ccol);
    }

    for (int kt = 0; kt < KD / 64; ++kt) {
        __syncthreads();
        if (kt < KD / 64 - 1) {
            int p = (kt + 1) & 1;
#pragma unroll
            for (int i = 0; i < 4; ++i) {
                *(u16x8*)&Al[p][crow + i * 32][ccol] = ra[i];
                *(u16x8*)&Bl[p][crow + i * 32][ccol] = rb[i];
            }
            int cn = (kt + 2 < KD / 64 ? kt + 2 : KD / 64 - 1) * 64;
#pragma unroll
            for (int i = 0; i < 4; ++i) {
                ra[i] = *(const u16x8*)(O   + (long)(m0 + crow + i * 32) * KD + cn + ccol);
                rb[i] = *(const u16x8*)(Wub + (long)(n0 + crow + i * 32) * KD + cn + ccol);
            }
        }
        int p = kt & 1;
        __builtin_amdgcn_s_setprio(1);
#pragma unroll
        for (int k16 = 0; k16 < 4; ++k16) {
            bf16x8 afr[2], bfr[2];
#pragma unroll
            for (int rb2 = 0; rb2 < 2; ++rb2)
                afr[rb2] = cast8(*(const u16x8*)&Al[p][wr * 64 + rb2 * 32 + m32][k16 * 16 + 8 * hi]);
#pragma unroll
            for (int cb2 = 0; cb2 < 2; ++cb2)
                bfr[cb2] = cast8(*(const u16x8*)&Bl[p][wc * 64 + cb2 * 32 + m32][k16 * 16 + 8 * hi]);
#pragma unroll
            for (int rb2 = 0; rb2 < 2; ++rb2)
#pragma unroll
                for (int cb2 = 0; cb2 < 2; ++cb2)
                    acc[rb2][cb2] = __builtin_amdgcn_mfma_f32_32x32x16_bf16(afr[rb2], bfr[cb2], acc[rb2][cb2], 0, 0, 0);
        }
        __builtin_amdgcn_s_setprio(0);
    }

    const float bv0 = bu[n0 + wc * 64 + m32];
    const float bv1 = bu[n0 + wc * 64 + 32 + m32];
#pragma unroll
    for (int rb2 = 0; rb2 < 2; ++rb2)
#pragma unroll
        for (int cb2 = 0; cb2 < 2; ++cb2) {
            float bv = cb2 ? bv1 : bv0;
            int nn = n0 + wc * 64 + cb2 * 32 + m32;
#pragma unroll
            for (int reg = 0; reg < 16; ++reg) {
                int mm = m0 + wr * 64 + rb2 * 32 + (reg & 3) + 8 * (reg >> 2) + 4 * hi;
                out[(long)mm * KD + nn] = acc[rb2][cb2][reg] + bv;
            }
        }
}

extern "C" void kernel_launch(void* const* d_in, const int* in_sizes, int n_in,
                              void* d_out, int out_size, void* d_ws, size_t ws_size,
                              hipStream_t stream) {
    const float* x  = (const float*)d_in[0];
    const float* Wq = (const float*)d_in[1];
    const float* Wk = (const float*)d_in[2];
    const float* Wv = (const float*)d_in[3];
    const float* Wu = (const float*)d_in[4];
    const float* bu = (const float*)d_in[5];
    float* out = (float*)d_out;

    u16* ws = (u16*)d_ws;
    const size_t SZ = (size_t)NB * NH * TB * HD;   // per-tensor bf16 elems
    u16* Q   = ws;
    u16* Kq  = ws + SZ;
    u16* VT  = ws + 2 * SZ;   // [bh][96][2048]
    u16* O   = ws + 3 * SZ;
    u16* Wub = ws;            // aliases Q (dead after attn; stream-ordered)

    const float inv4 = 1.0f / powf((float)KD, 0.25f);

    qkv_proj<<<dim3(TB / 64, NB * NH), dim3(256), 0, stream>>>(x, Wq, Wk, Wv, Q, Kq, VT, inv4);
    attn<<<dim3(TB / 256 * NB * NH), dim3(256), 0, stream>>>(Q, Kq, VT, O);
    wu_conv<<<dim3((KD * KD) / 1024), dim3(256), 0, stream>>>(Wu, Wub);
    out_gemm<<<dim3((NB * TB / 128) * (KD / 128)), dim3(256), 0, stream>>>(O, Wub, bu, out);
}

// Round 10
// 186.381 us; speedup vs baseline: 1.2457x; 1.2457x over previous
//
#include <hip/hip_runtime.h>
#include <hip/hip_bf16.h>
#include <math.h>

#define TB 2048   // sequence length
#define NB 4      // batch
#define NH 8      // heads
#define HD 96     // head dim
#define KD 768    // model dim

typedef unsigned short u16;
typedef __attribute__((ext_vector_type(4))) u16 u16x4;
typedef __attribute__((ext_vector_type(8))) u16 u16x8;
typedef __attribute__((ext_vector_type(4))) float f32x4;
typedef __attribute__((ext_vector_type(16))) float f32x16;
typedef __attribute__((ext_vector_type(4))) unsigned u32x4;
typedef __attribute__((ext_vector_type(8))) __bf16 bf16x8;

__device__ __forceinline__ u16 f2bf(float f) {
    unsigned u = __builtin_bit_cast(unsigned, f);
    u += 0x7FFFu + ((u >> 16) & 1u);   // RNE
    return (u16)(u >> 16);
}
__device__ __forceinline__ bf16x8 cast8(u16x8 u) { return __builtin_bit_cast(bf16x8, u); }
__device__ __forceinline__ unsigned pkbf(float a, float b) {
    unsigned w;
    asm("v_cvt_pk_bf16_f32 %0, %1, %2" : "=v"(w) : "v"(a), "v"(b));
    return w;
}

// ---------------------------------------------------------------------------
// Kernel W: one-time Wq/Wk/Wv fp32 -> bf16 (inv4 baked into Wq,Wk).
// Output lives in the head of d_out (overwritten later by out_gemm).
// grid = 27 blocks x 256 thr, 4 elems/thread (27648 total).
// ---------------------------------------------------------------------------
__global__ __launch_bounds__(256) void w_conv(
    const float* __restrict__ Wq, const float* __restrict__ Wk,
    const float* __restrict__ Wv, u16* __restrict__ Wb, float inv4)
{
    int i = (blockIdx.x * 256 + threadIdx.x) * 4;
    const float* src; float sc; int off;
    if (i < 9216)       { src = Wq; off = i;         sc = inv4; }
    else if (i < 18432) { src = Wk; off = i - 9216;  sc = inv4; }
    else                { src = Wv; off = i - 18432; sc = 1.0f; }
    f32x4 f = *(const f32x4*)(src + off);
    u16x4 o = { f2bf(f[0] * sc), f2bf(f[1] * sc), f2bf(f[2] * sc), f2bf(f[3] * sc) };
    *(u16x4*)(Wb + i) = o;
}

// ---------------------------------------------------------------------------
// Kernel A: QKV projection with LDS-repacked coalesced stores.
//   Q,K -> [bh][t][96] ; V -> [bh][96][t] (transposed via swapped MFMA).
// W arrives pre-converted bf16 (Wb = [3][96][96]); staged via b128.
// grid = (32 t-chunks, 32 bh), 256 thr.
// ---------------------------------------------------------------------------
__global__ __launch_bounds__(256) void qkv_proj(
    const float* __restrict__ x, const u16* __restrict__ Wb,
    u16* __restrict__ Q, u16* __restrict__ Kout, u16* __restrict__ VT)
{
    __shared__ __align__(16) u16 Wl[3][96][104];
    __shared__ __align__(16) u16 Rp[96 * 72];   // union: Q/K [64][104], V [96][72]
    const int tid = threadIdx.x;
#pragma unroll
    for (int ci = 0; ci < 14; ++ci) {
        int ch = tid + ci * 256;
        if (ch < 3456) {
            int m = ch / 1152, rem = ch % 1152;
            int rr = rem / 12, cc = (rem % 12) * 8;
            *(u16x8*)&Wl[m][rr][cc] = *(const u16x8*)(Wb + m * 9216 + rr * 96 + cc);
        }
    }
    __syncthreads();

    const int w = tid >> 6, l = tid & 63;
    const int lc = l & 15, lk = l >> 4;
    const int bh = blockIdx.y, b = bh >> 3, h = bh & 7;
    const int t0 = blockIdx.x * 64;
    const int tw = t0 + w * 16;

    bf16x8 afrag[3];
    {
        const float* xp = x + ((long)((b * TB + tw + lc) * NH + h)) * HD + 8 * lk;
#pragma unroll
        for (int c = 0; c < 3; ++c) {
            f32x4 f0 = *(const f32x4*)(xp + c * 32);
            f32x4 f1 = *(const f32x4*)(xp + c * 32 + 4);
            u16x8 u;
#pragma unroll
            for (int j = 0; j < 4; ++j) { u[j] = f2bf(f0[j]); u[4 + j] = f2bf(f1[j]); }
            afrag[c] = cast8(u);
        }
    }

    const f32x4 Z4 = {0.f, 0.f, 0.f, 0.f};
    u16* outs[2] = {Q, Kout};
#pragma unroll
    for (int m = 0; m < 2; ++m) {
        f32x4 acc[6];
#pragma unroll
        for (int nt = 0; nt < 6; ++nt) acc[nt] = Z4;
#pragma unroll
        for (int c = 0; c < 3; ++c) {
#pragma unroll
            for (int nt = 0; nt < 6; ++nt) {
                u16x8 bw = *(const u16x8*)&Wl[m][nt * 16 + lc][c * 32 + 8 * lk];
                acc[nt] = __builtin_amdgcn_mfma_f32_16x16x32_bf16(afrag[c], cast8(bw), acc[nt], 0, 0, 0);
            }
        }
        __syncthreads();   // Rp free (prior reads done)
#pragma unroll
        for (int nt = 0; nt < 6; ++nt)
#pragma unroll
            for (int reg = 0; reg < 4; ++reg)
                Rp[(w * 16 + lk * 4 + reg) * 104 + nt * 16 + lc] = f2bf(acc[nt][reg]);
        __syncthreads();
#pragma unroll
        for (int ci = 0; ci < 3; ++ci) {
            int ch = tid + ci * 256;
            int row = ch / 12, cc = (ch % 12) * 8;
            *(u16x8*)(outs[m] + ((long)bh * TB + t0 + row) * HD + cc) = *(const u16x8*)&Rp[row * 104 + cc];
        }
    }
    {   // V transposed: D[o][t] via swapped args
        f32x4 acc[6];
#pragma unroll
        for (int nt = 0; nt < 6; ++nt) acc[nt] = Z4;
#pragma unroll
        for (int c = 0; c < 3; ++c) {
#pragma unroll
            for (int nt = 0; nt < 6; ++nt) {
                u16x8 aw = *(const u16x8*)&Wl[2][nt * 16 + lc][c * 32 + 8 * lk];
                acc[nt] = __builtin_amdgcn_mfma_f32_16x16x32_bf16(cast8(aw), afrag[c], acc[nt], 0, 0, 0);
            }
        }
        __syncthreads();
#pragma unroll
        for (int nt = 0; nt < 6; ++nt)
#pragma unroll
            for (int reg = 0; reg < 4; ++reg) {
                int o = nt * 16 + lk * 4 + reg;
                Rp[o * 72 + w * 16 + lc] = f2bf(acc[nt][reg]);
            }
        __syncthreads();
#pragma unroll
        for (int ci = 0; ci < 3; ++ci) {
            int ch = tid + ci * 256;
            int row = ch >> 3, tc = (ch & 7) * 8;
            *(u16x8*)(VT + ((long)bh * HD + row) * TB + t0 + tc) = *(const u16x8*)&Rp[row * 72 + tc];
        }
    }
}

// ---------------------------------------------------------------------------
// Kernel B: flash attention, split-KV.  8 waves = 2 groups x 4; group g does
// s in [g*1024, (g+1)*1024).  q=64/wave (q-tile 256), KVB=64 staged (2 sub-
// steps of 32), per-group dbuf LDS, 1 barrier/step.  LDS merge epilogue.
// grid = 256 blocks (8 qtiles x 32 bh, XCD-swizzled), 512 thr.
// ---------------------------------------------------------------------------
#define KVB 64
#define VOFFA (KVB * 104)                 // 6656 elems
#define SLABA (KVB * 104 + HD * 72)       // 13568 elems (27136 B)

__global__ __launch_bounds__(512, 2) void attn(
    const u16* __restrict__ Q, const u16* __restrict__ Kin, const u16* __restrict__ VT,
    u16* __restrict__ O)
{
    __shared__ __align__(16) u16 SM[2][2][SLABA];   // [group][buf], 108544 B

    const int tid = threadIdx.x;
    const int w = tid >> 6, l = tid & 63;
    const int m32 = l & 31, hi = l >> 5;
    const int g = w >> 2, w2 = w & 3;
    const int lid = (blockIdx.x & 7) * 32 + (blockIdx.x >> 3);  // XCD swizzle
    const int qt = lid & 7, bh = lid >> 3;
    const int q0 = qt * 256 + w2 * 64;

    const u16* Qb = Q + (long)bh * TB * HD;
    const u16* Kb = Kin + (long)bh * TB * HD;
    const u16* Vb = VT + (long)bh * HD * TB;    // [d][t]

    // per-group staging: 6 b128 chunks/thread (K: 768 chunks, Vt: 768)
    const int ltid = tid & 255;
    const u16* gbase[6]; int loff[6]; int mult[6];
#pragma unroll
    for (int ci = 0; ci < 6; ++ci) {
        int ch = ltid + ci * 256;
        if (ch < 768) {
            int row = ch / 12, cc = (ch % 12) * 8;
            gbase[ci] = Kb + ((long)g * 1024 + row) * HD + cc;
            mult[ci] = HD;
            loff[ci] = row * 104 + cc;
        } else {
            int c2 = ch - 768;
            int d = c2 >> 3, sc = (c2 & 7) * 8;
            gbase[ci] = Vb + (long)d * TB + g * 1024 + sc;
            mult[ci] = 1;
            loff[ci] = VOFFA + d * 72 + sc;
        }
    }

    // Q B-fragments, 2 q-sets: col q = q0 + qs*32 + m32, k = kk*16 + 8*hi + j
    bf16x8 qb[2][6];
#pragma unroll
    for (int qs = 0; qs < 2; ++qs)
#pragma unroll
        for (int kk = 0; kk < 6; ++kk)
            qb[qs][kk] = cast8(*(const u16x8*)(Qb + (long)(q0 + qs * 32 + m32) * HD + kk * 16 + 8 * hi));

    // prologue: tile0 -> SM[g][0], prefetch tile1
    u16x8 r[6];
#pragma unroll
    for (int ci = 0; ci < 6; ++ci) r[ci] = *(const u16x8*)(gbase[ci]);
#pragma unroll
    for (int ci = 0; ci < 6; ++ci) *(u16x8*)(&SM[g][0][0] + loff[ci]) = r[ci];
#pragma unroll
    for (int ci = 0; ci < 6; ++ci) r[ci] = *(const u16x8*)(gbase[ci] + (long)KVB * mult[ci]);

    float m_st[2] = {-1e30f, -1e30f}, l_st[2] = {0.f, 0.f};
    f32x16 accO[3][2];                  // [d-tile][q-set]
#pragma unroll
    for (int dt = 0; dt < 3; ++dt)
#pragma unroll
        for (int qs = 0; qs < 2; ++qs)
#pragma unroll
            for (int rr = 0; rr < 16; ++rr) accO[dt][qs][rr] = 0.f;

    const int NST = 1024 / KVB;   // 16
    for (int st = 0; st < NST; ++st) {
        __syncthreads();
        if (st < NST - 1) {
            u16* dst = &SM[g][(st + 1) & 1][0];
#pragma unroll
            for (int ci = 0; ci < 6; ++ci) *(u16x8*)(dst + loff[ci]) = r[ci];
            int s2 = (st + 2 < NST ? st + 2 : NST - 1) * KVB;
#pragma unroll
            for (int ci = 0; ci < 6; ++ci) r[ci] = *(const u16x8*)(gbase[ci] + (long)s2 * mult[ci]);
        }
        const u16* KP = &SM[g][st & 1][0];
        const u16* VP = KP + VOFFA;

#pragma unroll
        for (int sub = 0; sub < 2; ++sub) {
            // S^T = K Q^T: one K read -> 2 MFMA (both q-sets)
            f32x16 sa[2];
#pragma unroll
            for (int qs = 0; qs < 2; ++qs)
#pragma unroll
                for (int rr = 0; rr < 16; ++rr) sa[qs][rr] = 0.f;
            __builtin_amdgcn_s_setprio(1);
#pragma unroll
            for (int kk = 0; kk < 6; ++kk) {
                u16x8 kf = *(const u16x8*)(KP + (sub * 32 + m32) * 104 + kk * 16 + 8 * hi);
                sa[0] = __builtin_amdgcn_mfma_f32_32x32x16_bf16(cast8(kf), qb[0][kk], sa[0], 0, 0, 0);
                sa[1] = __builtin_amdgcn_mfma_f32_32x32x16_bf16(cast8(kf), qb[1][kk], sa[1], 0, 0, 0);
            }
            __builtin_amdgcn_s_setprio(0);

            // online softmax per q-set
            float tm[2];
#pragma unroll
            for (int qs = 0; qs < 2; ++qs) {
                float t2 = sa[qs][0];
#pragma unroll
                for (int rr = 1; rr < 16; ++rr) t2 = fmaxf(t2, sa[qs][rr]);
                t2 = fmaxf(t2, __shfl_xor(t2, 32));
                tm[qs] = t2;
            }
            if (!__all(tm[0] - m_st[0] <= 8.0f && tm[1] - m_st[1] <= 8.0f)) {   // T13
#pragma unroll
                for (int qs = 0; qs < 2; ++qs) {
                    float mnew = fmaxf(m_st[qs], tm[qs]);
                    float alpha = __expf(m_st[qs] - mnew);
#pragma unroll
                    for (int dt = 0; dt < 3; ++dt)
#pragma unroll
                        for (int rr = 0; rr < 16; ++rr) accO[dt][qs][rr] *= alpha;
                    l_st[qs] *= alpha;
                    m_st[qs] = mnew;
                }
            }
#pragma unroll
            for (int qs = 0; qs < 2; ++qs) {
                float sum = 0.f;
#pragma unroll
                for (int rr = 0; rr < 16; ++rr) {
                    float pv = __expf(sa[qs][rr] - m_st[qs]);
                    sa[qs][rr] = pv;
                    sum += pv;
                }
                sum += __shfl_xor(sum, 32);
                l_st[qs] += sum;
            }

            // P -> bf16 B-fragments in-register
            bf16x8 pb0[2], pb1[2];
#pragma unroll
            for (int qs = 0; qs < 2; ++qs) {
                unsigned A1 = pkbf(sa[qs][0], sa[qs][1]);
                unsigned A2 = pkbf(sa[qs][2], sa[qs][3]);
                unsigned B1 = pkbf(sa[qs][4], sa[qs][5]);
                unsigned B2 = pkbf(sa[qs][6], sa[qs][7]);
                unsigned A3 = pkbf(sa[qs][8], sa[qs][9]);
                unsigned A4 = pkbf(sa[qs][10], sa[qs][11]);
                unsigned B3 = pkbf(sa[qs][12], sa[qs][13]);
                unsigned B4 = pkbf(sa[qs][14], sa[qs][15]);
                unsigned xA1 = __shfl_xor((int)A1, 32), xA2 = __shfl_xor((int)A2, 32);
                unsigned xB1 = __shfl_xor((int)B1, 32), xB2 = __shfl_xor((int)B2, 32);
                unsigned xA3 = __shfl_xor((int)A3, 32), xA4 = __shfl_xor((int)A4, 32);
                unsigned xB3 = __shfl_xor((int)B3, 32), xB4 = __shfl_xor((int)B4, 32);
                u32x4 t0v = { hi ? xB1 : A1, hi ? xB2 : A2, hi ? B1 : xA1, hi ? B2 : xA2 };
                u32x4 t1v = { hi ? xB3 : A3, hi ? xB4 : A4, hi ? B3 : xA3, hi ? B4 : xA4 };
                pb0[qs] = __builtin_bit_cast(bf16x8, t0v);
                pb1[qs] = __builtin_bit_cast(bf16x8, t1v);
            }

            // PV: one V read -> 2 MFMA
            __builtin_amdgcn_s_setprio(1);
#pragma unroll
            for (int dt = 0; dt < 3; ++dt) {
                u16x8 vf0 = *(const u16x8*)(VP + (dt * 32 + m32) * 72 + sub * 32 + 8 * hi);
                accO[dt][0] = __builtin_amdgcn_mfma_f32_32x32x16_bf16(cast8(vf0), pb0[0], accO[dt][0], 0, 0, 0);
                accO[dt][1] = __builtin_amdgcn_mfma_f32_32x32x16_bf16(cast8(vf0), pb0[1], accO[dt][1], 0, 0, 0);
                u16x8 vf1 = *(const u16x8*)(VP + (dt * 32 + m32) * 72 + sub * 32 + 16 + 8 * hi);
                accO[dt][0] = __builtin_amdgcn_mfma_f32_32x32x16_bf16(cast8(vf1), pb1[0], accO[dt][0], 0, 0, 0);
                accO[dt][1] = __builtin_amdgcn_mfma_f32_32x32x16_bf16(cast8(vf1), pb1[1], accO[dt][1], 0, 0, 0);
            }
            __builtin_amdgcn_s_setprio(0);
        }
    }

    // ---- merge the two KV-halves via LDS ----
    float* MB = (float*)&SM[0][0][0];   // [2g][4w][2qs][64l] m
    float* LB = MB + 1024;              // same layout, l
    float* OB = MB + 2048;              // [4w][64l][97] partial O (group 1)
    {
        int mi = ((g * 4 + w2) * 2) * 64 + l;
        MB[mi] = m_st[0]; MB[mi + 64] = m_st[1];
        LB[mi] = l_st[0]; LB[mi + 64] = l_st[1];
    }
    __syncthreads();
    float a_self[2], l_tot[2];
    {
        int pi = (((g ^ 1) * 4 + w2) * 2) * 64 + l;
#pragma unroll
        for (int qs = 0; qs < 2; ++qs) {
            float mo = MB[pi + qs * 64], lo = LB[pi + qs * 64];
            float mx = fmaxf(m_st[qs], mo);
            a_self[qs] = __expf(m_st[qs] - mx);
            float ao = __expf(mo - mx);
            l_tot[qs] = a_self[qs] * l_st[qs] + ao * lo;
        }
    }
    if (g == 1) {
        float* ob = OB + (w2 * 64 + l) * 97;
#pragma unroll
        for (int dt = 0; dt < 3; ++dt)
#pragma unroll
            for (int qs = 0; qs < 2; ++qs)
#pragma unroll
                for (int rr = 0; rr < 16; ++rr)
                    ob[(dt * 2 + qs) * 16 + rr] = accO[dt][qs][rr] * a_self[qs];
    }
    __syncthreads();
    if (g == 0) {
        const int b = bh >> 3, h = bh & 7;
        const float* ob = OB + (w2 * 64 + l) * 97;
#pragma unroll
        for (int qs = 0; qs < 2; ++qs) {
            float linv = 1.0f / l_tot[qs];
            int t = q0 + qs * 32 + m32;
            u16* op = O + ((long)(b * TB + t)) * KD + h * HD;
#pragma unroll
            for (int dt = 0; dt < 3; ++dt)
#pragma unroll
                for (int g4 = 0; g4 < 4; ++g4) {
                    u16x4 v;
#pragma unroll
                    for (int j = 0; j < 4; ++j) {
                        float pv = accO[dt][qs][g4 * 4 + j] * a_self[qs] + ob[(dt * 2 + qs) * 16 + g4 * 4 + j];
                        v[j] = f2bf(pv * linv);
                    }
                    *(u16x4*)(op + dt * 32 + g4 * 8 + 4 * hi) = v;
                }
        }
    }
}

// ---------------------------------------------------------------------------
// Kernel C0: one-time Wu fp32 -> bf16 (into dead Q workspace region)
// ---------------------------------------------------------------------------
__global__ __launch_bounds__(256) void wu_conv(const float* __restrict__ Wu, u16* __restrict__ Wub) {
    int i = (blockIdx.x * 256 + threadIdx.x) * 4;
    f32x4 f = *(const f32x4*)(Wu + i);
    u16x4 o = { f2bf(f[0]), f2bf(f[1]), f2bf(f[2]), f2bf(f[3]) };
    *(u16x4*)(Wub + i) = o;
}

// ---------------------------------------------------------------------------
// Kernel C: out = O @ Wub^T + bu.  128x128 tile, BK=64, 32x32 MFMA, dbuf
// single-barrier, reg-prefetch.  4 waves (2x2).  1D grid 384, XCD swizzle.
// ---------------------------------------------------------------------------
__global__ __launch_bounds__(256) void out_gemm(
    const u16* __restrict__ O, const u16* __restrict__ Wub,
    const float* __restrict__ bu, float* __restrict__ out)
{
    __shared__ __align__(16) u16 Al[2][128][68];
    __shared__ __align__(16) u16 Bl[2][128][68];
    const int tid = threadIdx.x;
    const int w = tid >> 6, l = tid & 63;
    const int m32 = l & 31, hi = l >> 5;
    const int wr = w >> 1, wc = w & 1;
    const int lid = (blockIdx.x & 7) * 48 + (blockIdx.x >> 3);
    const int nb = lid % 6, mb = lid / 6;
    const int m0 = mb * 128, n0 = nb * 128;

    const int crow = tid >> 3, ccol = (tid & 7) * 8;

    f32x16 acc[2][2];
#pragma unroll
    for (int i = 0; i < 2; ++i)
#pragma unroll
        for (int j = 0; j < 2; ++j)
#pragma unroll
            for (int rr = 0; rr < 16; ++rr) acc[i][j][rr] = 0.f;

    u16x8 ra[4], rb[4];
#pragma unroll
    for (int i = 0; i < 4; ++i) {
        ra[i] = *(const u16x8*)(O   + (long)(m0 + crow + i * 32) * KD + ccol);
        rb[i] = *(const u16x8*)(Wub + (long)(n0 + crow + i * 32) * KD + ccol);
    }
#pragma unroll
    for (int i = 0; i < 4; ++i) {
        *(u16x8*)&Al[0][crow + i * 32][ccol] = ra[i];
        *(u16x8*)&Bl[0][crow + i * 32][ccol] = rb[i];
    }
#pragma unroll
    for (int i = 0; i < 4; ++i) {
        ra[i] = *(const u16x8*)(O   + (long)(m0 + crow + i * 32) * KD + 64 + ccol);
        rb[i] = *(const u16x8*)(Wub + (long)(n0 + crow + i * 32) * KD + 64 + ccol);
    }

    for (int kt = 0; kt < KD / 64; ++kt) {
        __syncthreads();
        if (kt < KD / 64 - 1) {
            int p = (kt + 1) & 1;
#pragma unroll
            for (int i = 0; i < 4; ++i) {
                *(u16x8*)&Al[p][crow + i * 32][ccol] = ra[i];
                *(u16x8*)&Bl[p][crow + i * 32][ccol] = rb[i];
            }
            int cn = (kt + 2 < KD / 64 ? kt + 2 : KD / 64 - 1) * 64;
#pragma unroll
            for (int i = 0; i < 4; ++i) {
                ra[i] = *(const u16x8*)(O   + (long)(m0 + crow + i * 32) * KD + cn + ccol);
                rb[i] = *(const u16x8*)(Wub + (long)(n0 + crow + i * 32) * KD + cn + ccol);
            }
        }
        int p = kt & 1;
        __builtin_amdgcn_s_setprio(1);
#pragma unroll
        for (int k16 = 0; k16 < 4; ++k16) {
            bf16x8 afr[2], bfr[2];
#pragma unroll
            for (int rb2 = 0; rb2 < 2; ++rb2)
                afr[rb2] = cast8(*(const u16x8*)&Al[p][wr * 64 + rb2 * 32 + m32][k16 * 16 + 8 * hi]);
#pragma unroll
            for (int cb2 = 0; cb2 < 2; ++cb2)
                bfr[cb2] = cast8(*(const u16x8*)&Bl[p][wc * 64 + cb2 * 32 + m32][k16 * 16 + 8 * hi]);
#pragma unroll
            for (int rb2 = 0; rb2 < 2; ++rb2)
#pragma unroll
                for (int cb2 = 0; cb2 < 2; ++cb2)
                    acc[rb2][cb2] = __builtin_amdgcn_mfma_f32_32x32x16_bf16(afr[rb2], bfr[cb2], acc[rb2][cb2], 0, 0, 0);
        }
        __builtin_amdgcn_s_setprio(0);
    }

    const float bv0 = bu[n0 + wc * 64 + m32];
    const float bv1 = bu[n0 + wc * 64 + 32 + m32];
#pragma unroll
    for (int rb2 = 0; rb2 < 2; ++rb2)
#pragma unroll
        for (int cb2 = 0; cb2 < 2; ++cb2) {
            float bv = cb2 ? bv1 : bv0;
            int nn = n0 + wc * 64 + cb2 * 32 + m32;
#pragma unroll
            for (int reg = 0; reg < 16; ++reg) {
                int mm = m0 + wr * 64 + rb2 * 32 + (reg & 3) + 8 * (reg >> 2) + 4 * hi;
                out[(long)mm * KD + nn] = acc[rb2][cb2][reg] + bv;
            }
        }
}

extern "C" void kernel_launch(void* const* d_in, const int* in_sizes, int n_in,
                              void* d_out, int out_size, void* d_ws, size_t ws_size,
                              hipStream_t stream) {
    const float* x  = (const float*)d_in[0];
    const float* Wq = (const float*)d_in[1];
    const float* Wk = (const float*)d_in[2];
    const float* Wv = (const float*)d_in[3];
    const float* Wu = (const float*)d_in[4];
    const float* bu = (const float*)d_in[5];
    float* out = (float*)d_out;

    u16* ws = (u16*)d_ws;
    const size_t SZ = (size_t)NB * NH * TB * HD;   // per-tensor bf16 elems
    u16* Q   = ws;
    u16* Kq  = ws + SZ;
    u16* VT  = ws + 2 * SZ;   // [bh][96][2048]
    u16* O   = ws + 3 * SZ;
    u16* Wub = ws;            // aliases Q (dead after attn; stream-ordered)
    u16* Wb  = (u16*)d_out;   // qkv weights bf16 in d_out head (overwritten by out_gemm)

    const float inv4 = 1.0f / powf((float)KD, 0.25f);

    w_conv<<<dim3(27), dim3(256), 0, stream>>>(Wq, Wk, Wv, Wb, inv4);
    qkv_proj<<<dim3(TB / 64, NB * NH), dim3(256), 0, stream>>>(x, Wb, Q, Kq, VT);
    attn<<<dim3(TB / 256 * NB * NH), dim3(512), 0, stream>>>(Q, Kq, VT, O);
    wu_conv<<<dim3((KD * KD) / 1024), dim3(256), 0, stream>>>(Wu, Wub);
    out_gemm<<<dim3((NB * TB / 128) * (KD / 128)), dim3(256), 0, stream>>>(O, Wub, bu, out);
}